// Round 1
// baseline (726.842 us; speedup 1.0000x reference)
//
#include <hip/hip_runtime.h>
#include <stdint.h>

// CrossWinAttention fp32 baseline.
// Shapes: b=4 n=4 x=y=8 w1=w2=8 d=128, H=4 Dh=32, L=64 windows, NW=256 tokens/window, BH=16.
#define LN_EPS 1e-5f
#define SCALE 0.17677669529663687f   // 32^-0.5
#define KEEPQ 192
#define TOPKK 64

__device__ __forceinline__ float wredmax(float x) {
  #pragma unroll
  for (int m = 32; m; m >>= 1) x = fmaxf(x, __shfl_xor(x, m, 64));
  return x;
}
__device__ __forceinline__ float wredsum(float x) {
  #pragma unroll
  for (int m = 32; m; m >>= 1) x += __shfl_xor(x, m, 64);
  return x;
}

// Exact top-k over 256 values, 4 per lane (element index = lane + 64*s).
// Tie-break: smaller index wins (matches jax.lax.top_k stable sort).
// Must be called by all 64 lanes of a wave.
__device__ __forceinline__ void topk_sel(const float v[4], int k, int lane, bool sel[4]) {
  uint32_t u[4];
  #pragma unroll
  for (int s = 0; s < 4; ++s) {
    uint32_t bb = __float_as_uint(v[s]);
    if ((bb & 0x7FFFFFFFu) == 0u) bb = 0u;               // -0 -> +0 (IEEE equal)
    u[s] = (bb & 0x80000000u) ? ~bb : (bb | 0x80000000u); // order-preserving map
  }
  uint32_t prefix = 0u;
  bool exact = false;
  for (int bit = 31; bit >= 0; --bit) {
    uint32_t cand = prefix | (1u << bit);
    int c = 0;
    #pragma unroll
    for (int s = 0; s < 4; ++s) c += __popcll(__ballot(u[s] >= cand));
    if (c >= k) {
      prefix = cand;
      if (c == k) { exact = true; break; }   // set uniquely determined
    }
  }
  if (exact) {
    #pragma unroll
    for (int s = 0; s < 4; ++s) sel[s] = (u[s] >= prefix);
    return;
  }
  const uint32_t T = prefix;                 // k-th largest mapped value
  int gt = 0;
  unsigned long long eb[4];
  #pragma unroll
  for (int s = 0; s < 4; ++s) {
    gt += __popcll(__ballot(u[s] > T));
    eb[s] = __ballot(u[s] == T);
  }
  const int need = k - gt;                   // >=1 by construction
  const unsigned long long lm = (1ull << lane) - 1ull;
  int base = 0;
  #pragma unroll
  for (int s = 0; s < 4; ++s) {
    int before = base + __popcll(eb[s] & lm);
    sel[s] = (u[s] > T) || ((u[s] == T) && (before < need));
    base += __popcll(eb[s]);
  }
}

// ---------------- Kernel 1: LN + QKV projection ----------------
// grid (1024, 3): 64 tokens per block, blockIdx.y picks tensor {q,k,v}.
// Writes head layout: out[((bh*64+l)*256 + j)*32 + dh], bh=b*4+h, l=x*8+y, j=n*64+w1*8+w2.
__global__ __launch_bounds__(256) void k_lnproj(
    const float* __restrict__ xq, const float* __restrict__ xk, const float* __restrict__ xv,
    const float* __restrict__ gq, const float* __restrict__ beq,
    const float* __restrict__ gk, const float* __restrict__ bek,
    const float* __restrict__ gv, const float* __restrict__ bev,
    const float* __restrict__ wq, const float* __restrict__ biq,
    const float* __restrict__ wk, const float* __restrict__ bik,
    const float* __restrict__ wv, const float* __restrict__ biv,
    float* __restrict__ qh, float* __restrict__ kh, float* __restrict__ vh)
{
  __shared__ float xs[64 * 132];
  const int tile = blockIdx.x;
  const int t = blockIdx.y;
  const float* x  = (t == 0) ? xq : (t == 1) ? xk : xv;
  const float* g  = (t == 0) ? gq : (t == 1) ? gk : gv;
  const float* be = (t == 0) ? beq : (t == 1) ? bek : bev;
  const float* W  = (t == 0) ? wq : (t == 1) ? wk : wv;
  const float* bi = (t == 0) ? biq : (t == 1) ? bik : biv;
  float* out      = (t == 0) ? qh : (t == 1) ? kh : vh;
  const int tid = threadIdx.x;

  // stage 64 tokens x 128 dims
  const float4* xg = (const float4*)(x + (size_t)tile * 64 * 128);
  #pragma unroll
  for (int i = 0; i < 8; ++i) {
    int idx = tid + i * 256;            // float4 index, 2048 total
    int r = idx >> 5;                   // 32 float4 per row
    int c = (idx & 31) * 4;
    *(float4*)&xs[r * 132 + c] = xg[idx];
  }
  __syncthreads();

  // LayerNorm: 4 threads per token (consecutive lanes)
  {
    int r = tid >> 2, p = tid & 3;
    float s = 0.f, sq = 0.f;
    #pragma unroll
    for (int c = 0; c < 32; ++c) {
      float vv = xs[r * 132 + p * 32 + c];
      s += vv; sq += vv * vv;
    }
    s += __shfl_xor(s, 1, 64); sq += __shfl_xor(sq, 1, 64);
    s += __shfl_xor(s, 2, 64); sq += __shfl_xor(sq, 2, 64);
    float mean = s * (1.0f / 128.0f);
    float var = sq * (1.0f / 128.0f) - mean * mean;   // biased, matches torch/jax var
    float rstd = rsqrtf(var + LN_EPS);
    #pragma unroll
    for (int c = 0; c < 32; ++c) {
      int cc = p * 32 + c;
      xs[r * 132 + cc] = (xs[r * 132 + cc] - mean) * rstd * g[cc] + be[cc];
    }
  }
  __syncthreads();

  // GEMM 64x128 = xs(64x128) @ W(128x128); thread tile 4 rows x 8 cols
  const int ty = tid >> 4, tx = tid & 15;
  float acc[4][8];
  #pragma unroll
  for (int i = 0; i < 4; ++i)
    #pragma unroll
    for (int j = 0; j < 8; ++j) acc[i][j] = 0.f;

  #pragma unroll 4
  for (int kk = 0; kk < 128; ++kk) {
    float a[4];
    #pragma unroll
    for (int i = 0; i < 4; ++i) a[i] = xs[(ty * 4 + i) * 132 + kk];
    const float4 w0 = *(const float4*)&W[kk * 128 + tx * 8];
    const float4 w1 = *(const float4*)&W[kk * 128 + tx * 8 + 4];
    #pragma unroll
    for (int i = 0; i < 4; ++i) {
      acc[i][0] = fmaf(a[i], w0.x, acc[i][0]);
      acc[i][1] = fmaf(a[i], w0.y, acc[i][1]);
      acc[i][2] = fmaf(a[i], w0.z, acc[i][2]);
      acc[i][3] = fmaf(a[i], w0.w, acc[i][3]);
      acc[i][4] = fmaf(a[i], w1.x, acc[i][4]);
      acc[i][5] = fmaf(a[i], w1.y, acc[i][5]);
      acc[i][6] = fmaf(a[i], w1.z, acc[i][6]);
      acc[i][7] = fmaf(a[i], w1.w, acc[i][7]);
    }
  }

  float bias[8];
  #pragma unroll
  for (int j = 0; j < 8; ++j) bias[j] = bi[tx * 8 + j];
  const int h = tx >> 2;              // (tx*8)/32
  const int dh0 = (tx & 3) * 8;
  #pragma unroll
  for (int i = 0; i < 4; ++i) {
    int gt_ = tile * 64 + ty * 4 + i;
    int b  = gt_ >> 14;
    int n  = (gt_ >> 12) & 3;
    int xx = (gt_ >> 9) & 7;
    int yy = (gt_ >> 6) & 7;
    int w1i = (gt_ >> 3) & 7;
    int w2i = gt_ & 7;
    int l = xx * 8 + yy;
    int j = n * 64 + w1i * 8 + w2i;
    size_t off = ((size_t)((b * 4 + h) * 64 + l) * 256 + j) * 32 + dh0;
    float4 o0 = make_float4(acc[i][0] + bias[0], acc[i][1] + bias[1],
                            acc[i][2] + bias[2], acc[i][3] + bias[3]);
    float4 o1 = make_float4(acc[i][4] + bias[4], acc[i][5] + bias[5],
                            acc[i][6] + bias[6], acc[i][7] + bias[7]);
    *(float4*)&out[off] = o0;
    *(float4*)&out[off + 4] = o1;
  }
}

// ---------------- Kernel 2: windowed attention ----------------
// One block per (bh,l). 512 threads, ~150 KB LDS.
__global__ __launch_bounds__(512) void k_attn(
    const float* __restrict__ qh, const float* __restrict__ kh, const float* __restrict__ vh,
    float* __restrict__ abar)
{
  __shared__ float ks[256 * 36];
  __shared__ float vs[256 * 36];
  __shared__ float Ss[64 * 257];
  __shared__ float qs[64 * 36];
  __shared__ float sal[256];
  __shared__ float qkeep[256];   // SCALE if kept else 0

  const int blk = blockIdx.x;            // bh*64 + l
  const int bh = blk >> 6, l = blk & 63;
  const int b = bh >> 2, h = bh & 3;
  const int tid = threadIdx.x;
  const int lane = tid & 63, wvid = tid >> 6;
  const size_t base = (size_t)blk * 256 * 32;

  // stage K, V
  const float4* kg = (const float4*)(kh + base);
  const float4* vg = (const float4*)(vh + base);
  #pragma unroll
  for (int i = 0; i < 4; ++i) {
    int idx = tid + i * 512;        // 2048 float4
    int r = idx >> 3, c = (idx & 7) * 4;
    *(float4*)&ks[r * 36 + c] = kg[idx];
    *(float4*)&vs[r * 36 + c] = vg[idx];
  }
  // query saliency (pre-scale, pre-mask qh)
  if (tid < 256) {
    const float4* qg = (const float4*)(qh + base + (size_t)tid * 32);
    float s = 0.f;
    #pragma unroll
    for (int i = 0; i < 8; ++i) {
      float4 vv = qg[i];
      s += vv.x * vv.x + vv.y * vv.y + vv.z * vv.z + vv.w * vv.w;
    }
    sal[tid] = s;
  }
  __syncthreads();
  if (tid < 64) {   // wave 0: top-192 saliency selection
    float v[4]; bool sel[4];
    #pragma unroll
    for (int s = 0; s < 4; ++s) v[s] = sal[tid + 64 * s];
    topk_sel(v, KEEPQ, tid, sel);
    #pragma unroll
    for (int s = 0; s < 4; ++s) qkeep[tid + 64 * s] = sel[s] ? SCALE : 0.0f;
  }
  __syncthreads();

  float facc[4] = {0.f, 0.f, 0.f, 0.f};
  const int pq = tid >> 3;            // PV: output row (w index)
  const int pc = (tid & 7) * 4;       // PV: dh0
  const int ty = tid >> 5, tx = tid & 31;  // QK tile coords

  for (int ch = 0; ch < 4; ++ch) {    // chunk = one n value
    // load scaled+masked q chunk
    {
      int r = tid >> 3, c = (tid & 7) * 4;
      float4 vq = *(const float4*)(qh + base + (size_t)(ch * 64 + r) * 32 + c);
      float kf = qkeep[ch * 64 + r];
      vq.x *= kf; vq.y *= kf; vq.z *= kf; vq.w *= kf;
      *(float4*)&qs[r * 36 + c] = vq;
    }
    __syncthreads();

    // S(64x256) = qs @ ks^T ; thread tile 4 rows x 8 cols (cols tx + 32j)
    {
      float acc[4][8];
      #pragma unroll
      for (int i = 0; i < 4; ++i)
        #pragma unroll
        for (int j = 0; j < 8; ++j) acc[i][j] = 0.f;
      #pragma unroll
      for (int kk = 0; kk < 32; kk += 4) {
        float4 a4[4], b4[8];
        #pragma unroll
        for (int i = 0; i < 4; ++i) a4[i] = *(const float4*)&qs[(ty * 4 + i) * 36 + kk];
        #pragma unroll
        for (int j = 0; j < 8; ++j) b4[j] = *(const float4*)&ks[(tx + 32 * j) * 36 + kk];
        #pragma unroll
        for (int i = 0; i < 4; ++i)
          #pragma unroll
          for (int j = 0; j < 8; ++j)
            acc[i][j] += a4[i].x * b4[j].x + a4[i].y * b4[j].y +
                         a4[i].z * b4[j].z + a4[i].w * b4[j].w;
      }
      #pragma unroll
      for (int i = 0; i < 4; ++i)
        #pragma unroll
        for (int j = 0; j < 8; ++j)
          Ss[(ty * 4 + i) * 257 + tx + 32 * j] = acc[i][j];
    }
    __syncthreads();

    // top-64 + softmax, 8 rows per wave
    for (int rr = 0; rr < 8; ++rr) {
      int r = wvid * 8 + rr;
      float v[4]; bool sel[4];
      #pragma unroll
      for (int s = 0; s < 4; ++s) v[s] = Ss[r * 257 + lane + 64 * s];
      topk_sel(v, TOPKK, lane, sel);
      float m = fmaxf(fmaxf(v[0], v[1]), fmaxf(v[2], v[3]));
      m = wredmax(m);   // global max is always in the top-64
      float e[4], sum = 0.f;
      #pragma unroll
      for (int s = 0; s < 4; ++s) { e[s] = sel[s] ? __expf(v[s] - m) : 0.0f; sum += e[s]; }
      sum = wredsum(sum);
      float inv = 1.0f / sum;
      #pragma unroll
      for (int s = 0; s < 4; ++s) Ss[r * 257 + lane + 64 * s] = e[s] * inv;
    }
    __syncthreads();

    // PV: accumulate a[q][dh] over this chunk (n = ch); n-mean folded via facc
    #pragma unroll 8
    for (int kx = 0; kx < 256; ++kx) {
      float a = Ss[pq * 257 + kx];
      const float4 vv = *(const float4*)&vs[kx * 36 + pc];
      facc[0] = fmaf(a, vv.x, facc[0]);
      facc[1] = fmaf(a, vv.y, facc[1]);
      facc[2] = fmaf(a, vv.z, facc[2]);
      facc[3] = fmaf(a, vv.w, facc[3]);
    }
    __syncthreads();
  }

  // abar[(b*64+l)*64 + w][h*32+dh] = mean over n
  size_t o = ((size_t)((b * 64 + l) * 64 + pq)) * 128 + h * 32 + pc;
  float4 ov = make_float4(facc[0] * 0.25f, facc[1] * 0.25f, facc[2] * 0.25f, facc[3] * 0.25f);
  *(float4*)&abar[o] = ov;
}

// ---------------- Kernel 3: final projection ----------------
// out(16384x128) = abar @ w_proj + b_proj  (output layout == d_out layout)
__global__ __launch_bounds__(256) void k_proj(
    const float* __restrict__ abar, const float* __restrict__ W,
    const float* __restrict__ bi, float* __restrict__ out)
{
  __shared__ float xs[64 * 132];
  const int tile = blockIdx.x;
  const int tid = threadIdx.x;
  const float4* xg = (const float4*)(abar + (size_t)tile * 64 * 128);
  #pragma unroll
  for (int i = 0; i < 8; ++i) {
    int idx = tid + i * 256;
    int r = idx >> 5, c = (idx & 31) * 4;
    *(float4*)&xs[r * 132 + c] = xg[idx];
  }
  __syncthreads();

  const int ty = tid >> 4, tx = tid & 15;
  float acc[4][8];
  #pragma unroll
  for (int i = 0; i < 4; ++i)
    #pragma unroll
    for (int j = 0; j < 8; ++j) acc[i][j] = 0.f;

  #pragma unroll 4
  for (int kk = 0; kk < 128; ++kk) {
    float a[4];
    #pragma unroll
    for (int i = 0; i < 4; ++i) a[i] = xs[(ty * 4 + i) * 132 + kk];
    const float4 w0 = *(const float4*)&W[kk * 128 + tx * 8];
    const float4 w1 = *(const float4*)&W[kk * 128 + tx * 8 + 4];
    #pragma unroll
    for (int i = 0; i < 4; ++i) {
      acc[i][0] = fmaf(a[i], w0.x, acc[i][0]);
      acc[i][1] = fmaf(a[i], w0.y, acc[i][1]);
      acc[i][2] = fmaf(a[i], w0.z, acc[i][2]);
      acc[i][3] = fmaf(a[i], w0.w, acc[i][3]);
      acc[i][4] = fmaf(a[i], w1.x, acc[i][4]);
      acc[i][5] = fmaf(a[i], w1.y, acc[i][5]);
      acc[i][6] = fmaf(a[i], w1.z, acc[i][6]);
      acc[i][7] = fmaf(a[i], w1.w, acc[i][7]);
    }
  }
  #pragma unroll
  for (int i = 0; i < 4; ++i) {
    size_t row = (size_t)tile * 64 + ty * 4 + i;
    float4 o0 = make_float4(acc[i][0] + bi[tx * 8 + 0], acc[i][1] + bi[tx * 8 + 1],
                            acc[i][2] + bi[tx * 8 + 2], acc[i][3] + bi[tx * 8 + 3]);
    float4 o1 = make_float4(acc[i][4] + bi[tx * 8 + 4], acc[i][5] + bi[tx * 8 + 5],
                            acc[i][6] + bi[tx * 8 + 6], acc[i][7] + bi[tx * 8 + 7]);
    *(float4*)&out[row * 128 + tx * 8] = o0;
    *(float4*)&out[row * 128 + tx * 8 + 4] = o1;
  }
}

extern "C" void kernel_launch(void* const* d_in, const int* in_sizes, int n_in,
                              void* d_out, int out_size, void* d_ws, size_t ws_size,
                              hipStream_t stream) {
  (void)in_sizes; (void)n_in; (void)out_size; (void)ws_size;
  const float* xq   = (const float*)d_in[0];
  const float* xk   = (const float*)d_in[1];
  const float* xv   = (const float*)d_in[2];
  const float* gq   = (const float*)d_in[3];
  const float* beq  = (const float*)d_in[4];
  const float* gk   = (const float*)d_in[5];
  const float* bek  = (const float*)d_in[6];
  const float* gv   = (const float*)d_in[7];
  const float* bev  = (const float*)d_in[8];
  const float* wq   = (const float*)d_in[9];
  const float* biq  = (const float*)d_in[10];
  const float* wk   = (const float*)d_in[11];
  const float* bik  = (const float*)d_in[12];
  const float* wv   = (const float*)d_in[13];
  const float* biv  = (const float*)d_in[14];
  const float* wpr  = (const float*)d_in[15];
  const float* bpr  = (const float*)d_in[16];

  float* qh = (float*)d_ws;                 // 16*64*256*32 = 8388608 floats
  float* kh = qh + 8388608;
  float* vh = kh + 8388608;
  float* abar = vh + 8388608;               // 16384*128 = 2097152 floats
  // total ws use: 104 MB

  k_lnproj<<<dim3(1024, 3), 256, 0, stream>>>(xq, xk, xv, gq, beq, gk, bek, gv, bev,
                                              wq, biq, wk, bik, wv, biv, qh, kh, vh);
  k_attn<<<1024, 512, 0, stream>>>(qh, kh, vh, abar);
  k_proj<<<256, 256, 0, stream>>>(abar, wpr, bpr, (float*)d_out);
}

// Round 2
// 448.268 us; speedup vs baseline: 1.6214x; 1.6214x over previous
//
#include <hip/hip_runtime.h>
#include <stdint.h>

// CrossWinAttention: b=4 n=4 x=y=8 w1=w2=8 d=128, H=4 Dh=32, L=64, NW=256, BH=16.
#define LN_EPS 1e-5f
#define SCALE 0.17677669529663687f   // 32^-0.5
#define KEEPQ 192

typedef __attribute__((ext_vector_type(8))) short short8v;   // 8 bf16
typedef __attribute__((ext_vector_type(4))) float float4v;

__device__ __forceinline__ short f2bf(float x) {             // RNE f32->bf16
  uint32_t u = __float_as_uint(x);
  uint32_t r = (u + 0x7FFFu + ((u >> 16) & 1u)) >> 16;
  return (short)r;
}
__device__ __forceinline__ float bf2f(short s) {
  return __uint_as_float(((uint32_t)(uint16_t)s) << 16);
}
__device__ __forceinline__ uint32_t pk2(short a, short b) {
  return (uint32_t)(uint16_t)a | ((uint32_t)(uint16_t)b << 16);
}
__device__ __forceinline__ void split3(float x, short &h, short &m, short &l) {
  h = f2bf(x); float r1 = x - bf2f(h);
  m = f2bf(r1); float r2 = r1 - bf2f(m);
  l = f2bf(r2);
}

// Exact top-k over 256 values, 4 per lane (element index = lane + 64*s).
// Tie-break: smaller index wins (matches jax.lax.top_k stable sort).
__device__ __forceinline__ void topk_sel(const float v[4], int k, int lane, bool sel[4]) {
  uint32_t u[4];
  #pragma unroll
  for (int s = 0; s < 4; ++s) {
    uint32_t bb = __float_as_uint(v[s]);
    if ((bb & 0x7FFFFFFFu) == 0u) bb = 0u;
    u[s] = (bb & 0x80000000u) ? ~bb : (bb | 0x80000000u);
  }
  uint32_t prefix = 0u;
  bool exact = false;
  for (int bit = 31; bit >= 0; --bit) {
    uint32_t cand = prefix | (1u << bit);
    int c = 0;
    #pragma unroll
    for (int s = 0; s < 4; ++s) c += __popcll(__ballot(u[s] >= cand));
    if (c >= k) {
      prefix = cand;
      if (c == k) { exact = true; break; }
    }
  }
  if (exact) {
    #pragma unroll
    for (int s = 0; s < 4; ++s) sel[s] = (u[s] >= prefix);
    return;
  }
  const uint32_t T = prefix;
  int gt = 0;
  unsigned long long eb[4];
  #pragma unroll
  for (int s = 0; s < 4; ++s) {
    gt += __popcll(__ballot(u[s] > T));
    eb[s] = __ballot(u[s] == T);
  }
  const int need = k - gt;
  const unsigned long long lm = (1ull << lane) - 1ull;
  int base = 0;
  #pragma unroll
  for (int s = 0; s < 4; ++s) {
    int before = base + __popcll(eb[s] & lm);
    sel[s] = (u[s] > T) || ((u[s] == T) && (before < need));
    base += __popcll(eb[s]);
  }
}

// ---------------- Kernel 1: LN + QKV projection (unchanged, fp32) ----------------
__global__ __launch_bounds__(256) void k_lnproj(
    const float* __restrict__ xq, const float* __restrict__ xk, const float* __restrict__ xv,
    const float* __restrict__ gq, const float* __restrict__ beq,
    const float* __restrict__ gk, const float* __restrict__ bek,
    const float* __restrict__ gv, const float* __restrict__ bev,
    const float* __restrict__ wq, const float* __restrict__ biq,
    const float* __restrict__ wk, const float* __restrict__ bik,
    const float* __restrict__ wv, const float* __restrict__ biv,
    float* __restrict__ qh, float* __restrict__ kh, float* __restrict__ vh)
{
  __shared__ float xs[64 * 132];
  const int tile = blockIdx.x;
  const int t = blockIdx.y;
  const float* x  = (t == 0) ? xq : (t == 1) ? xk : xv;
  const float* g  = (t == 0) ? gq : (t == 1) ? gk : gv;
  const float* be = (t == 0) ? beq : (t == 1) ? bek : bev;
  const float* W  = (t == 0) ? wq : (t == 1) ? wk : wv;
  const float* bi = (t == 0) ? biq : (t == 1) ? bik : biv;
  float* out      = (t == 0) ? qh : (t == 1) ? kh : vh;
  const int tid = threadIdx.x;

  const float4* xg = (const float4*)(x + (size_t)tile * 64 * 128);
  #pragma unroll
  for (int i = 0; i < 8; ++i) {
    int idx = tid + i * 256;
    int r = idx >> 5;
    int c = (idx & 31) * 4;
    *(float4*)&xs[r * 132 + c] = xg[idx];
  }
  __syncthreads();

  {
    int r = tid >> 2, p = tid & 3;
    float s = 0.f, sq = 0.f;
    #pragma unroll
    for (int c = 0; c < 32; ++c) {
      float vv = xs[r * 132 + p * 32 + c];
      s += vv; sq += vv * vv;
    }
    s += __shfl_xor(s, 1, 64); sq += __shfl_xor(sq, 1, 64);
    s += __shfl_xor(s, 2, 64); sq += __shfl_xor(sq, 2, 64);
    float mean = s * (1.0f / 128.0f);
    float var = sq * (1.0f / 128.0f) - mean * mean;
    float rstd = rsqrtf(var + LN_EPS);
    #pragma unroll
    for (int c = 0; c < 32; ++c) {
      int cc = p * 32 + c;
      xs[r * 132 + cc] = (xs[r * 132 + cc] - mean) * rstd * g[cc] + be[cc];
    }
  }
  __syncthreads();

  const int ty = tid >> 4, tx = tid & 15;
  float acc[4][8];
  #pragma unroll
  for (int i = 0; i < 4; ++i)
    #pragma unroll
    for (int j = 0; j < 8; ++j) acc[i][j] = 0.f;

  #pragma unroll 4
  for (int kk = 0; kk < 128; ++kk) {
    float a[4];
    #pragma unroll
    for (int i = 0; i < 4; ++i) a[i] = xs[(ty * 4 + i) * 132 + kk];
    const float4 w0 = *(const float4*)&W[kk * 128 + tx * 8];
    const float4 w1 = *(const float4*)&W[kk * 128 + tx * 8 + 4];
    #pragma unroll
    for (int i = 0; i < 4; ++i) {
      acc[i][0] = fmaf(a[i], w0.x, acc[i][0]);
      acc[i][1] = fmaf(a[i], w0.y, acc[i][1]);
      acc[i][2] = fmaf(a[i], w0.z, acc[i][2]);
      acc[i][3] = fmaf(a[i], w0.w, acc[i][3]);
      acc[i][4] = fmaf(a[i], w1.x, acc[i][4]);
      acc[i][5] = fmaf(a[i], w1.y, acc[i][5]);
      acc[i][6] = fmaf(a[i], w1.z, acc[i][6]);
      acc[i][7] = fmaf(a[i], w1.w, acc[i][7]);
    }
  }

  float bias[8];
  #pragma unroll
  for (int j = 0; j < 8; ++j) bias[j] = bi[tx * 8 + j];
  const int h = tx >> 2;
  const int dh0 = (tx & 3) * 8;
  #pragma unroll
  for (int i = 0; i < 4; ++i) {
    int gt_ = tile * 64 + ty * 4 + i;
    int b  = gt_ >> 14;
    int n  = (gt_ >> 12) & 3;
    int xx = (gt_ >> 9) & 7;
    int yy = (gt_ >> 6) & 7;
    int w1i = (gt_ >> 3) & 7;
    int w2i = gt_ & 7;
    int l = xx * 8 + yy;
    int j = n * 64 + w1i * 8 + w2i;
    size_t off = ((size_t)((b * 4 + h) * 64 + l) * 256 + j) * 32 + dh0;
    float4 o0 = make_float4(acc[i][0] + bias[0], acc[i][1] + bias[1],
                            acc[i][2] + bias[2], acc[i][3] + bias[3]);
    float4 o1 = make_float4(acc[i][4] + bias[4], acc[i][5] + bias[5],
                            acc[i][6] + bias[6], acc[i][7] + bias[7]);
    *(float4*)&out[off] = o0;
    *(float4*)&out[off + 4] = o1;
  }
}

// ---------------- Kernel 2: windowed attention (MFMA rewrite) ----------------
// One block per (bh,l). 512 threads = 8 waves. Chunks of 32 queries, 8 chunks.
// QK^T: bf16x3 split, 6 MFMA products (fp32-emulation, exact top-k selection).
// PV: bf16 MFMA. topk: 4 rows/wave group-parallel binary search.
__global__ __launch_bounds__(512) void k_attn(
    const float* __restrict__ qh, const float* __restrict__ kh, const float* __restrict__ vh,
    float* __restrict__ abar)
{
  __shared__ __align__(16) short ksh[3][256][40];   // K bf16 hi/mid/lo, 61440 B
  __shared__ __align__(16) short vts[32][264];      // V^T bf16, 16896 B
  __shared__ __align__(16) float Ss[32][260];       // S chunk fp32, 33280 B
  __shared__ __align__(16) short qpbuf[32 * 264];   // Q splits (3*32*40) then P bf16 (32*264)
  __shared__ float sal[256];
  __shared__ float qkeep[256];

  const int blk = blockIdx.x;            // bh*64 + l
  const int bh = blk >> 6, l = blk & 63;
  const int b = bh >> 2, h = bh & 3;
  const int tid = threadIdx.x;
  const int lane = tid & 63, wv = tid >> 6;
  const int g = lane >> 4, p = lane & 15;
  const size_t base = (size_t)blk * 256 * 32;

  // ---- stage K (bf16x3) + V (bf16 transposed) ----
  {
    const float4* kg = (const float4*)(kh + base);
    const float4* vg = (const float4*)(vh + base);
    #pragma unroll
    for (int i = 0; i < 4; ++i) {
      int idx = tid + i * 512;           // 2048 float4
      int r = idx >> 3, c4 = (idx & 7) * 4;
      float4 kvv = kg[idx];
      float xv[4] = {kvv.x, kvv.y, kvv.z, kvv.w};
      short hh[4], mh[4], lh[4];
      #pragma unroll
      for (int t = 0; t < 4; ++t) split3(xv[t], hh[t], mh[t], lh[t]);
      *(uint2*)&ksh[0][r][c4] = make_uint2(pk2(hh[0], hh[1]), pk2(hh[2], hh[3]));
      *(uint2*)&ksh[1][r][c4] = make_uint2(pk2(mh[0], mh[1]), pk2(mh[2], mh[3]));
      *(uint2*)&ksh[2][r][c4] = make_uint2(pk2(lh[0], lh[1]), pk2(lh[2], lh[3]));
      float4 vvv = vg[idx];
      vts[c4 + 0][r] = f2bf(vvv.x);
      vts[c4 + 1][r] = f2bf(vvv.y);
      vts[c4 + 2][r] = f2bf(vvv.z);
      vts[c4 + 3][r] = f2bf(vvv.w);
    }
  }
  // query saliency
  if (tid < 256) {
    const float4* qg2 = (const float4*)(qh + base + (size_t)tid * 32);
    float s = 0.f;
    #pragma unroll
    for (int i = 0; i < 8; ++i) {
      float4 vv = qg2[i];
      s += vv.x * vv.x + vv.y * vv.y + vv.z * vv.z + vv.w * vv.w;
    }
    sal[tid] = s;
  }
  __syncthreads();
  if (tid < 64) {                        // wave 0: exact top-192 saliency
    float v[4]; bool selq[4];
    #pragma unroll
    for (int s = 0; s < 4; ++s) v[s] = sal[tid + 64 * s];
    topk_sel(v, KEEPQ, tid, selq);
    #pragma unroll
    for (int s = 0; s < 4; ++s) qkeep[tid + 64 * s] = selq[s] ? SCALE : 0.0f;
  }
  __syncthreads();

  // cache V^T B-fragments (per-wave output col tile = wv&1), reused all chunks
  short8v vfrag[8];
  #pragma unroll
  for (int kk = 0; kk < 8; ++kk)
    vfrag[kk] = *(const short8v*)&vts[(wv & 1) * 16 + p][kk * 32 + g * 8];

  float4v accp = {0.f, 0.f, 0.f, 0.f};   // PV accumulator (n-sum)

  const int rt = wv & 1;                 // QK: q row-tile (of 2)
  const int ctb = (wv >> 1) * 4;         // QK: key col-tile base (4 of 16)

  for (int ch = 0; ch < 8; ++ch) {
    // ---- stage Q chunk: scale+mask, bf16x3 split ----
    if (tid < 256) {
      int r = tid >> 3, c4 = (tid & 7) * 4;
      const float4* qg = (const float4*)(qh + base + (size_t)(ch * 32 + r) * 32);
      float4 qv = qg[tid & 7];
      float kf = qkeep[ch * 32 + r];
      float xv[4] = {qv.x * kf, qv.y * kf, qv.z * kf, qv.w * kf};
      short hh[4], mh[4], lh[4];
      #pragma unroll
      for (int t = 0; t < 4; ++t) split3(xv[t], hh[t], mh[t], lh[t]);
      *(uint2*)&qpbuf[0 * 1280 + r * 40 + c4] = make_uint2(pk2(hh[0], hh[1]), pk2(hh[2], hh[3]));
      *(uint2*)&qpbuf[1 * 1280 + r * 40 + c4] = make_uint2(pk2(mh[0], mh[1]), pk2(mh[2], mh[3]));
      *(uint2*)&qpbuf[2 * 1280 + r * 40 + c4] = make_uint2(pk2(lh[0], lh[1]), pk2(lh[2], lh[3]));
    }
    __syncthreads();

    // ---- QK^T: S(32x256) via 6-pass bf16x3 MFMA ----
    {
      short8v aq0 = *(const short8v*)&qpbuf[0 * 1280 + (rt * 16 + p) * 40 + g * 8];
      short8v aq1 = *(const short8v*)&qpbuf[1 * 1280 + (rt * 16 + p) * 40 + g * 8];
      short8v aq2 = *(const short8v*)&qpbuf[2 * 1280 + (rt * 16 + p) * 40 + g * 8];
      #pragma unroll
      for (int c = 0; c < 4; ++c) {
        const int key = (ctb + c) * 16 + p;
        short8v b0 = *(const short8v*)&ksh[0][key][g * 8];
        short8v b1 = *(const short8v*)&ksh[1][key][g * 8];
        short8v b2 = *(const short8v*)&ksh[2][key][g * 8];
        float4v acc = {0.f, 0.f, 0.f, 0.f};
        acc = __builtin_amdgcn_mfma_f32_16x16x32_bf16(aq0, b0, acc, 0, 0, 0);
        acc = __builtin_amdgcn_mfma_f32_16x16x32_bf16(aq1, b0, acc, 0, 0, 0);
        acc = __builtin_amdgcn_mfma_f32_16x16x32_bf16(aq2, b0, acc, 0, 0, 0);
        acc = __builtin_amdgcn_mfma_f32_16x16x32_bf16(aq0, b1, acc, 0, 0, 0);
        acc = __builtin_amdgcn_mfma_f32_16x16x32_bf16(aq1, b1, acc, 0, 0, 0);
        acc = __builtin_amdgcn_mfma_f32_16x16x32_bf16(aq0, b2, acc, 0, 0, 0);
        #pragma unroll
        for (int r = 0; r < 4; ++r)
          Ss[rt * 16 + g * 4 + r][(ctb + c) * 16 + p] = acc[r];
      }
    }
    __syncthreads();

    // ---- top-64 + softmax -> P bf16 (4 rows/wave, 16-lane group per row) ----
    {
      const int row = wv * 4 + g;                     // 0..31
      const float kf = qkeep[ch * 32 + row];
      if (kf == 0.0f) {
        // pruned query: logits all exactly 0 -> uniform 1/64 over first 64 keys
        const uint32_t uni = pk2(f2bf(0.015625f), f2bf(0.015625f));
        *(uint2*)&qpbuf[row * 264 + 0 * 64 + 4 * p] = make_uint2(uni, uni);
        *(uint2*)&qpbuf[row * 264 + 1 * 64 + 4 * p] = make_uint2(0u, 0u);
        *(uint2*)&qpbuf[row * 264 + 2 * 64 + 4 * p] = make_uint2(0u, 0u);
        *(uint2*)&qpbuf[row * 264 + 3 * 64 + 4 * p] = make_uint2(0u, 0u);
      } else {
        // lane p owns cols {64s + 4p + t}
        float pv[16]; uint32_t u[16];
        #pragma unroll
        for (int s = 0; s < 4; ++s) {
          float4 t4 = *(const float4*)&Ss[row][s * 64 + 4 * p];
          pv[s * 4 + 0] = t4.x; pv[s * 4 + 1] = t4.y;
          pv[s * 4 + 2] = t4.z; pv[s * 4 + 3] = t4.w;
        }
        #pragma unroll
        for (int j = 0; j < 16; ++j) {
          uint32_t bb = __float_as_uint(pv[j]);
          if ((bb & 0x7FFFFFFFu) == 0u) bb = 0u;
          u[j] = (bb & 0x80000000u) ? ~bb : (bb | 0x80000000u);
        }
        float fm = pv[0];
        uint32_t umax = u[0], umin = u[0];
        #pragma unroll
        for (int j = 1; j < 16; ++j) {
          fm = fmaxf(fm, pv[j]);
          umax = max(umax, u[j]); umin = min(umin, u[j]);
        }
        #pragma unroll
        for (int d = 1; d < 16; d <<= 1) {
          fm = fmaxf(fm, __shfl_xor(fm, d, 16));
          umax = max(umax, (uint32_t)__shfl_xor((int)umax, d, 16));
          umin = min(umin, (uint32_t)__shfl_xor((int)umin, d, 16));
        }
        uint32_t T; int cnt;
        uint32_t diff = umax ^ umin;
        if (diff == 0u) { T = umax; cnt = 256; }
        else {
          int sb = 31 - __clz(diff);
          uint32_t piv = (sb >= 31) ? 0u : (umax & (0xFFFFFFFFu << (sb + 1)));
          cnt = 256;
          bool done = false;
          for (int bi = sb; bi >= 0; --bi) {
            uint32_t cand = piv | (1u << bi);
            int c = 0;
            #pragma unroll
            for (int j = 0; j < 16; ++j) c += (u[j] >= cand) ? 1 : 0;
            #pragma unroll
            for (int d = 1; d < 16; d <<= 1) c += __shfl_xor(c, d, 16);
            if (!done && c >= 64) { piv = cand; cnt = c; if (c == 64) done = true; }
            if (__all(done)) break;
          }
          T = piv;
        }
        uint32_t selm = 0;
        if (cnt == 64) {
          #pragma unroll
          for (int j = 0; j < 16; ++j) selm |= (u[j] >= T) ? (1u << j) : 0u;
        } else {
          // ties at threshold: keep first (64-gt) equals in column order
          int gt = 0;
          #pragma unroll
          for (int j = 0; j < 16; ++j) gt += (u[j] > T) ? 1 : 0;
          #pragma unroll
          for (int d = 1; d < 16; d <<= 1) gt += __shfl_xor(gt, d, 16);
          int need = 64 - gt;
          uint32_t eqm = 0;
          #pragma unroll
          for (int j = 0; j < 16; ++j) eqm |= (u[j] == T) ? (1u << j) : 0u;
          uint32_t ebp = 0;
          #pragma unroll
          for (int s = 0; s < 4; ++s)
            ebp |= (uint32_t)__popc((eqm >> (4 * s)) & 0xFu) << (8 * s);
          uint32_t scn = ebp;                        // inclusive scan over group lanes
          #pragma unroll
          for (int d = 1; d < 16; d <<= 1) {
            uint32_t tt = (uint32_t)__shfl_up((int)scn, d, 16);
            if (p >= d) scn += tt;
          }
          uint32_t tot = (uint32_t)__shfl((int)scn, 15, 16);
          uint32_t exl = scn - ebp;
          int run1 = (int)(tot & 0xFFu);
          int run2 = run1 + (int)((tot >> 8) & 0xFFu);
          int run3 = run2 + (int)((tot >> 16) & 0xFFu);
          int run[4] = {0, run1, run2, run3};
          #pragma unroll
          for (int s = 0; s < 4; ++s) {
            #pragma unroll
            for (int t = 0; t < 4; ++t) {
              int j = s * 4 + t;
              bool sel = false;
              if (u[j] > T) sel = true;
              else if (u[j] == T) {
                int pre = run[s] + (int)((exl >> (8 * s)) & 0xFFu)
                        + __popc((eqm >> (4 * s)) & ((1u << t) - 1u));
                sel = (pre < need);
              }
              selm |= sel ? (1u << j) : 0u;
            }
          }
        }
        // softmax over selected
        float e[16]; float esum = 0.f;
        #pragma unroll
        for (int j = 0; j < 16; ++j) {
          e[j] = ((selm >> j) & 1u) ? __expf(pv[j] - fm) : 0.0f;
          esum += e[j];
        }
        #pragma unroll
        for (int d = 1; d < 16; d <<= 1) esum += __shfl_xor(esum, d, 16);
        float inv = 1.0f / esum;
        #pragma unroll
        for (int s = 0; s < 4; ++s) {
          short p0 = f2bf(e[s * 4 + 0] * inv), p1 = f2bf(e[s * 4 + 1] * inv);
          short p2 = f2bf(e[s * 4 + 2] * inv), p3 = f2bf(e[s * 4 + 3] * inv);
          *(uint2*)&qpbuf[row * 264 + s * 64 + 4 * p] = make_uint2(pk2(p0, p1), pk2(p2, p3));
        }
      }
    }
    __syncthreads();

    // ---- PV: waves whose output rows match this chunk's w-half ----
    if ((wv >> 2) == (ch & 1)) {
      const int rtl = (wv >> 1) & 1;
      #pragma unroll
      for (int kk = 0; kk < 8; ++kk) {
        short8v pa = *(const short8v*)&qpbuf[(rtl * 16 + p) * 264 + kk * 32 + g * 8];
        accp = __builtin_amdgcn_mfma_f32_16x16x32_bf16(pa, vfrag[kk], accp, 0, 0, 0);
      }
    }
    __syncthreads();
  }

  // ---- write abar = mean over n ----
  {
    const int wrow = (wv >> 1) * 16 + g * 4;
    const int dh = (wv & 1) * 16 + p;
    #pragma unroll
    for (int r = 0; r < 4; ++r) {
      size_t o = ((size_t)((b * 64 + l) * 64 + wrow + r)) * 128 + h * 32 + dh;
      abar[o] = accp[r] * 0.25f;
    }
  }
}

// ---------------- Kernel 3: final projection (unchanged) ----------------
__global__ __launch_bounds__(256) void k_proj(
    const float* __restrict__ abar, const float* __restrict__ W,
    const float* __restrict__ bi, float* __restrict__ out)
{
  __shared__ float xs[64 * 132];
  const int tile = blockIdx.x;
  const int tid = threadIdx.x;
  const float4* xg = (const float4*)(abar + (size_t)tile * 64 * 128);
  #pragma unroll
  for (int i = 0; i < 8; ++i) {
    int idx = tid + i * 256;
    int r = idx >> 5, c = (idx & 31) * 4;
    *(float4*)&xs[r * 132 + c] = xg[idx];
  }
  __syncthreads();

  const int ty = tid >> 4, tx = tid & 15;
  float acc[4][8];
  #pragma unroll
  for (int i = 0; i < 4; ++i)
    #pragma unroll
    for (int j = 0; j < 8; ++j) acc[i][j] = 0.f;

  #pragma unroll 4
  for (int kk = 0; kk < 128; ++kk) {
    float a[4];
    #pragma unroll
    for (int i = 0; i < 4; ++i) a[i] = xs[(ty * 4 + i) * 132 + kk];
    const float4 w0 = *(const float4*)&W[kk * 128 + tx * 8];
    const float4 w1 = *(const float4*)&W[kk * 128 + tx * 8 + 4];
    #pragma unroll
    for (int i = 0; i < 4; ++i) {
      acc[i][0] = fmaf(a[i], w0.x, acc[i][0]);
      acc[i][1] = fmaf(a[i], w0.y, acc[i][1]);
      acc[i][2] = fmaf(a[i], w0.z, acc[i][2]);
      acc[i][3] = fmaf(a[i], w0.w, acc[i][3]);
      acc[i][4] = fmaf(a[i], w1.x, acc[i][4]);
      acc[i][5] = fmaf(a[i], w1.y, acc[i][5]);
      acc[i][6] = fmaf(a[i], w1.z, acc[i][6]);
      acc[i][7] = fmaf(a[i], w1.w, acc[i][7]);
    }
  }
  #pragma unroll
  for (int i = 0; i < 4; ++i) {
    size_t row = (size_t)tile * 64 + ty * 4 + i;
    float4 o0 = make_float4(acc[i][0] + bi[tx * 8 + 0], acc[i][1] + bi[tx * 8 + 1],
                            acc[i][2] + bi[tx * 8 + 2], acc[i][3] + bi[tx * 8 + 3]);
    float4 o1 = make_float4(acc[i][4] + bi[tx * 8 + 4], acc[i][5] + bi[tx * 8 + 5],
                            acc[i][6] + bi[tx * 8 + 6], acc[i][7] + bi[tx * 8 + 7]);
    *(float4*)&out[row * 128 + tx * 8] = o0;
    *(float4*)&out[row * 128 + tx * 8 + 4] = o1;
  }
}

extern "C" void kernel_launch(void* const* d_in, const int* in_sizes, int n_in,
                              void* d_out, int out_size, void* d_ws, size_t ws_size,
                              hipStream_t stream) {
  (void)in_sizes; (void)n_in; (void)out_size; (void)ws_size;
  const float* xq   = (const float*)d_in[0];
  const float* xk   = (const float*)d_in[1];
  const float* xv   = (const float*)d_in[2];
  const float* gq   = (const float*)d_in[3];
  const float* beq  = (const float*)d_in[4];
  const float* gk   = (const float*)d_in[5];
  const float* bek  = (const float*)d_in[6];
  const float* gv   = (const float*)d_in[7];
  const float* bev  = (const float*)d_in[8];
  const float* wq   = (const float*)d_in[9];
  const float* biq  = (const float*)d_in[10];
  const float* wk   = (const float*)d_in[11];
  const float* bik  = (const float*)d_in[12];
  const float* wv   = (const float*)d_in[13];
  const float* biv  = (const float*)d_in[14];
  const float* wpr  = (const float*)d_in[15];
  const float* bpr  = (const float*)d_in[16];

  float* qh = (float*)d_ws;                 // 16*64*256*32 floats
  float* kh = qh + 8388608;
  float* vh = kh + 8388608;
  float* abar = vh + 8388608;               // 16384*128 floats

  k_lnproj<<<dim3(1024, 3), 256, 0, stream>>>(xq, xk, xv, gq, beq, gk, bek, gv, bev,
                                              wq, biq, wk, bik, wv, biv, qh, kh, vh);
  k_attn<<<1024, 512, 0, stream>>>(qh, kh, vh, abar);
  k_proj<<<256, 256, 0, stream>>>(abar, wpr, bpr, (float*)d_out);
}